// Round 15
// baseline (480.402 us; speedup 1.0000x reference)
//
#include <hip/hip_runtime.h>
#include <hip/hip_bf16.h>

typedef _Float16 half8 __attribute__((ext_vector_type(8)));
typedef _Float16 half4v __attribute__((ext_vector_type(4)));
typedef float floatx4 __attribute__((ext_vector_type(4)));
typedef float floatx16 __attribute__((ext_vector_type(16)));

// ---------------------------------------------------------------------------
// Swizzled LDS layouts (chunk = 8 halfs = 16B, rotated by row).
// R15: 32-row block tile. act buffer: 32x256 fp16 (16 KiB, in-place).
// x buffer: 32x64 fp16 (4 KiB). Total 20480 B -> 6 blocks/CU at (256,6)
// (reg-capped; LDS would allow 8).
// ---------------------------------------------------------------------------
__device__ __forceinline__ int swz(int row, int col) {
    return row * 256 + ((((col >> 3) + row) & 31) << 3) + (col & 7);
}
__device__ __forceinline__ int xswz(int row, int col) {
    return row * 64 + ((((col >> 3) + row) & 7) << 3) + (col & 7);
}

// ---------------------------------------------------------------------------
// Weight pre-pack (unchanged, proven R5-R14): fp32 (K,N) row-major -> fp16
// fragment order; lane L holds W[kt*16 + 8*(L>>5) + j][nt*32 + (L&31)].
// Fed to the MFMA *A* operand so D = C^T. K zero-padded: L1 39->64 (KT=4),
// L5 295->320 (KT=20), others 256 (KT=16). L9 N 4->32. Tile starts (1KB):
// {0,32,160,288,416,576,704,832,960}, total 976 tiles = 999424 B in d_ws.
// ---------------------------------------------------------------------------
__global__ void pack_w32(const float* __restrict__ w1, const float* __restrict__ w2,
                         const float* __restrict__ w3, const float* __restrict__ w4,
                         const float* __restrict__ w5, const float* __restrict__ w6,
                         const float* __restrict__ w7, const float* __restrict__ w8,
                         const float* __restrict__ w9, _Float16* __restrict__ dst) {
    const int tileStart[10] = {0, 32, 160, 288, 416, 576, 704, 832, 960, 976};
    const int Ks[9] = {39, 256, 256, 256, 295, 256, 256, 256, 256};
    const int Ns[9] = {256, 256, 256, 256, 256, 256, 256, 256, 4};
    const int Tn[9] = {8, 8, 8, 8, 8, 8, 8, 8, 1};
    const float* ws[9] = {w1, w2, w3, w4, w5, w6, w7, w8, w9};

    int g = blockIdx.x * blockDim.x + threadIdx.x;
    int tile = g >> 6, lane = g & 63;
    if (tile >= 976) return;
    int layer = 0;
    while (tile >= tileStart[layer + 1]) layer++;
    int t = tile - tileStart[layer];
    int tn = Tn[layer];
    int kt = t / tn, nt = t - kt * tn;
    int k0 = kt * 16 + (lane >> 5) * 8;
    int n = nt * 32 + (lane & 31);
    const float* w = ws[layer];
    int K = Ks[layer], N = Ns[layer];
    _Float16 v[8];
#pragma unroll
    for (int j = 0; j < 8; j++) {
        int k = k0 + j;
        v[j] = (k < K && n < N) ? (_Float16)w[k * N + n] : (_Float16)0.f;
    }
    *(half8*)(dst + (size_t)tile * 512 + lane * 8) = *(half8*)v;
}

// A-fragment read for k-step ks, rows 0..31 (MFMA B operand).
// AMODE 0: act buffer. 1: ks>=KS0 from x buffer. 2: entirely x buffer.
template <int AMODE, int KS0>
__device__ __forceinline__ half8 loadA1(const _Float16* abuf,
                                        const _Float16* __restrict__ xbuf,
                                        int ks, int l31, int lhi) {
    if (AMODE == 2 || (AMODE == 1 && ks >= KS0)) {
        int c = ((AMODE == 2) ? ks : (ks - KS0)) * 16 + lhi * 8;
        return *(const half8*)(xbuf + xswz(l31, c));
    } else {
        int c = ks * 16 + lhi * 8;
        return *(const half8*)(abuf + swz(l31, c));
    }
}

// ---------------------------------------------------------------------------
// One fused layer: C(32x256) = relu(A(32xK) @ W + b), in-place LDS->LDS.
// R15: wave tile = 1m x 2n (32 rows x 64 cols) -> acc only 32 AGPR, so the
// proven R13 loop (unroll x2, depth-2 W ring, bias-in-acc, b64 epilogue)
// fits a (256,6) budget (96 total: 32 acc + ~46 arch) -> 6 blocks/CU =
// 24 waves/CU = 6 waves/SIMD (1.5x R13's TLP; R13's 64-AGPR acc capped TLP
// at 16 waves/CU, the mapped corner of the design space). Cost: W amortized
// over 32 rows -> 2x L2 W-traffic (~28 TB/s agg, 81% of ceiling) — this
// round tests whether TLP or W-queueing is the binding constraint.
// ---------------------------------------------------------------------------
template <int KT, int AMODE, int KS0>
__device__ __forceinline__ void layerT(const _Float16* abuf,
                                       const _Float16* __restrict__ xbuf,
                                       const half8* __restrict__ wq,
                                       const float* __restrict__ bias,
                                       _Float16* obuf,
                                       int lane, int wave) {
    static_assert((KT & 3) == 0 && KT >= 4, "KT must be a multiple of 4");
    const int l31 = lane & 31, lhi = lane >> 5;
    // W frag (kstep ks, n-tile wave*2+n): wl[ks*512 + n*64]
    const half8* wl = wq + (wave * 2) * 64 + lane;
    // Bias -> acc init: acc{0,1} element g*4+r is output channel
    // n = wave*64 + {0,32} + lhi*4 + g*8 + r.
    floatx16 acc0, acc1;
#pragma unroll
    for (int g = 0; g < 4; g++) {
        floatx4 b0 = *(const floatx4*)(bias + wave * 64 + lhi * 4 + g * 8);
        floatx4 b1 = *(const floatx4*)(bias + wave * 64 + 32 + lhi * 4 + g * 8);
#pragma unroll
        for (int r = 0; r < 4; r++) { acc0[g * 4 + r] = b0[r]; acc1[g * 4 + r] = b1[r]; }
    }
    half8 w0a = wl[0], w0b = wl[64];
    half8 w1a = wl[512], w1b = wl[512 + 64];
#pragma unroll 1
    for (int ks = 0; ks < KT - 4; ks += 4) {
        half8 w2a = wl[(ks + 2) * 512], w2b = wl[(ks + 2) * 512 + 64];
        half8 w3a = wl[(ks + 3) * 512], w3b = wl[(ks + 3) * 512 + 64];
        half8 a = loadA1<AMODE, KS0>(abuf, xbuf, ks, l31, lhi);
        acc0 = __builtin_amdgcn_mfma_f32_32x32x16_f16(w0a, a, acc0, 0, 0, 0);
        acc1 = __builtin_amdgcn_mfma_f32_32x32x16_f16(w0b, a, acc1, 0, 0, 0);
        a = loadA1<AMODE, KS0>(abuf, xbuf, ks + 1, l31, lhi);
        acc0 = __builtin_amdgcn_mfma_f32_32x32x16_f16(w1a, a, acc0, 0, 0, 0);
        acc1 = __builtin_amdgcn_mfma_f32_32x32x16_f16(w1b, a, acc1, 0, 0, 0);
        w0a = wl[(ks + 4) * 512]; w0b = wl[(ks + 4) * 512 + 64];
        w1a = wl[(ks + 5) * 512]; w1b = wl[(ks + 5) * 512 + 64];
        a = loadA1<AMODE, KS0>(abuf, xbuf, ks + 2, l31, lhi);
        acc0 = __builtin_amdgcn_mfma_f32_32x32x16_f16(w2a, a, acc0, 0, 0, 0);
        acc1 = __builtin_amdgcn_mfma_f32_32x32x16_f16(w2b, a, acc1, 0, 0, 0);
        a = loadA1<AMODE, KS0>(abuf, xbuf, ks + 3, l31, lhi);
        acc0 = __builtin_amdgcn_mfma_f32_32x32x16_f16(w3a, a, acc0, 0, 0, 0);
        acc1 = __builtin_amdgcn_mfma_f32_32x32x16_f16(w3b, a, acc1, 0, 0, 0);
    }
    {   // tail: last 4 k-steps (w0/w1 hold KT-4, KT-3)
        half8 w2a = wl[(KT - 2) * 512], w2b = wl[(KT - 2) * 512 + 64];
        half8 w3a = wl[(KT - 1) * 512], w3b = wl[(KT - 1) * 512 + 64];
        half8 a = loadA1<AMODE, KS0>(abuf, xbuf, KT - 4, l31, lhi);
        acc0 = __builtin_amdgcn_mfma_f32_32x32x16_f16(w0a, a, acc0, 0, 0, 0);
        acc1 = __builtin_amdgcn_mfma_f32_32x32x16_f16(w0b, a, acc1, 0, 0, 0);
        a = loadA1<AMODE, KS0>(abuf, xbuf, KT - 3, l31, lhi);
        acc0 = __builtin_amdgcn_mfma_f32_32x32x16_f16(w1a, a, acc0, 0, 0, 0);
        acc1 = __builtin_amdgcn_mfma_f32_32x32x16_f16(w1b, a, acc1, 0, 0, 0);
        a = loadA1<AMODE, KS0>(abuf, xbuf, KT - 2, l31, lhi);
        acc0 = __builtin_amdgcn_mfma_f32_32x32x16_f16(w2a, a, acc0, 0, 0, 0);
        acc1 = __builtin_amdgcn_mfma_f32_32x32x16_f16(w2b, a, acc1, 0, 0, 0);
        a = loadA1<AMODE, KS0>(abuf, xbuf, KT - 1, l31, lhi);
        acc0 = __builtin_amdgcn_mfma_f32_32x32x16_f16(w3a, a, acc0, 0, 0, 0);
        acc1 = __builtin_amdgcn_mfma_f32_32x32x16_f16(w3b, a, acc1, 0, 0, 0);
    }
    // In-place safety barrier: all waves' act-reads complete before any write.
    if (AMODE != 2) __syncthreads();
    // Epilogue: relu + fp16 cvt + b64 writes (bias already in acc).
    // D=C^T: row m = l31, col n = wave*64 + ni*32 + lhi*4 + g*8 + r.
    const int row = l31;
#pragma unroll
    for (int ni = 0; ni < 2; ni++) {
#pragma unroll
        for (int g = 0; g < 4; g++) {
            int col = wave * 64 + ni * 32 + lhi * 4 + g * 8;
            const floatx16& accv = ni ? acc1 : acc0;
            half4v h;
#pragma unroll
            for (int r = 0; r < 4; r++) {
                float v = accv[g * 4 + r];
                v = v > 0.f ? v : 0.f;
                h[r] = (_Float16)v;
            }
            *(half4v*)(obuf + swz(row, col)) = h;
        }
    }
}

// Layer 9 (swapped): 256 -> 4 (N padded to 32). Wave 0 handles the single
// 32-row m-tile; D[n][m]: lanes 0..31 hold n=r (r<4) for row m=l31.
__device__ __forceinline__ void layer9T(const _Float16* abuf,
                                        const half8* __restrict__ wq,
                                        const float* __restrict__ b9,
                                        float* __restrict__ out, long r0,
                                        int lane, int wave) {
    if (wave != 0) return;
    const int l31 = lane & 31, lhi = lane >> 5;
    floatx16 acc = {};
    const half8* wl = wq + lane;
    half8 wc = wl[0];
#pragma unroll 1
    for (int ks = 0; ks < 15; ks++) {
        half8 wn = wl[(ks + 1) * 64];
        half8 a = *(const half8*)(abuf + swz(l31, ks * 16 + lhi * 8));
        acc = __builtin_amdgcn_mfma_f32_32x32x16_f16(wc, a, acc, 0, 0, 0);
        wc = wn;
    }
    {
        half8 a = *(const half8*)(abuf + swz(l31, 15 * 16 + lhi * 8));
        acc = __builtin_amdgcn_mfma_f32_32x32x16_f16(wc, a, acc, 0, 0, 0);
    }
    if (lhi == 0) {
        asm volatile("" ::: "memory");
        floatx4 b4 = *(const floatx4*)(b9);
        floatx4 o;
#pragma unroll
        for (int r = 0; r < 4; r++) o[r] = acc[r] + b4[r];
        *(floatx4*)(out + (r0 + l31) * 4) = o;
    }
}

__global__ __launch_bounds__(256, 6) void mlp_fused(
    const float* __restrict__ x, const _Float16* __restrict__ wpk,
    const float* __restrict__ b1, const float* __restrict__ b2,
    const float* __restrict__ b3, const float* __restrict__ b4,
    const float* __restrict__ b5, const float* __restrict__ b6,
    const float* __restrict__ b7, const float* __restrict__ b8,
    const float* __restrict__ b9, float* __restrict__ out) {
    // 16 KiB act buffer + 4 KiB x tile = 20480 B; 4-wave blocks;
    // 6 blocks/CU (reg-capped by (256,6): 96 total regs/wave) = 24 waves/CU.
    __shared__ _Float16 lds[32 * 256 + 32 * 64];
    _Float16* buf = lds;
    _Float16* xbuf = lds + 32 * 256;
    const int tid = threadIdx.x;
    const int lane = tid & 63, wave = tid >> 6;
    const long r0 = (long)blockIdx.x * 32;

    // Stage x: zero pad cols (39..63) and fill cols 0..38 — disjoint, one barrier.
    for (int i = tid; i < 32 * 25; i += 256) {
        int row = i / 25, col = 39 + (i - row * 25);
        xbuf[xswz(row, col)] = (_Float16)0.f;
    }
    for (int i = tid; i < 32 * 39; i += 256) {
        int row = i / 39, col = i - row * 39;
        xbuf[xswz(row, col)] = (_Float16)x[r0 * 39 + i];  // contiguous 1248 floats
    }
    __syncthreads();

    const half8* wp = (const half8*)wpk;  // tile = 64 half8 (1 KB)
    const half8* w1q = wp + (size_t)0 * 64;
    const half8* w2q = wp + (size_t)32 * 64;
    const half8* w3q = wp + (size_t)160 * 64;
    const half8* w4q = wp + (size_t)288 * 64;
    const half8* w5q = wp + (size_t)416 * 64;
    const half8* w6q = wp + (size_t)576 * 64;
    const half8* w7q = wp + (size_t)704 * 64;
    const half8* w8q = wp + (size_t)832 * 64;
    const half8* w9q = wp + (size_t)960 * 64;

    layerT<4, 2, 0>(xbuf, xbuf, w1q, b1, buf, lane, wave);   // x -> buf
    __syncthreads();
    layerT<16, 0, 0>(buf, xbuf, w2q, b2, buf, lane, wave);
    __syncthreads();
    layerT<16, 0, 0>(buf, xbuf, w3q, b3, buf, lane, wave);
    __syncthreads();
    layerT<16, 0, 0>(buf, xbuf, w4q, b4, buf, lane, wave);
    __syncthreads();
    layerT<20, 1, 16>(buf, xbuf, w5q, b5, buf, lane, wave);  // [h|x] skip
    __syncthreads();
    layerT<16, 0, 0>(buf, xbuf, w6q, b6, buf, lane, wave);
    __syncthreads();
    layerT<16, 0, 0>(buf, xbuf, w7q, b7, buf, lane, wave);
    __syncthreads();
    layerT<16, 0, 0>(buf, xbuf, w8q, b8, buf, lane, wave);
    __syncthreads();
    layer9T(buf, w9q, b9, out, r0, lane, wave);
}

extern "C" void kernel_launch(void* const* d_in, const int* in_sizes, int n_in,
                              void* d_out, int out_size, void* d_ws, size_t ws_size,
                              hipStream_t stream) {
    const float* x = (const float*)d_in[0];
    const float* w[9];
    const float* b[9];
    for (int i = 0; i < 9; i++) {
        w[i] = (const float*)d_in[1 + 2 * i];
        b[i] = (const float*)d_in[2 + 2 * i];
    }
    _Float16* wpk = (_Float16*)d_ws;  // 999424 B

    pack_w32<<<244, 256, 0, stream>>>(w[0], w[1], w[2], w[3], w[4], w[5], w[6], w[7], w[8], wpk);
    mlp_fused<<<262144 / 32, 256, 0, stream>>>(x, wpk, b[0], b[1], b[2], b[3], b[4],
                                               b[5], b[6], b[7], b[8], (float*)d_out);
}

// Round 16
// 364.398 us; speedup vs baseline: 1.3183x; 1.3183x over previous
//
#include <hip/hip_runtime.h>
#include <hip/hip_bf16.h>

typedef _Float16 half8 __attribute__((ext_vector_type(8)));
typedef _Float16 half4v __attribute__((ext_vector_type(4)));
typedef float floatx4 __attribute__((ext_vector_type(4)));
typedef float floatx16 __attribute__((ext_vector_type(16)));

// ---------------------------------------------------------------------------
// R16: CHUNK-MAJOR act layout (replaces the rotation swizzle).
//   off(row, col) = (col>>3)*512 + row*8 + (col&7)   [halfs; 64-row tiles]
// A-fragment read for (ks, lhi, row): offset = (ks*2+lhi)*512 + row*8 —
// LINEAR in ks => one base VGPR + 16-bit immediate offsets for ALL ksteps
// (ks*1024 halfs = ks*2048 B <= 31744 B). Kills the per-read swz() VALU
// chain (~250 VALU/wave/layer, R13's VALUBusy=34%) and unchains ds_read
// addresses so the scheduler can hoist them (free pipelining).
// Bank math: reads hit ((c+?)*4)%32 patterns identical in collision count
// (4-way = b128 width floor) to the old swizzle; writes ~2-way. No change.
// act buffer: 64x256 fp16 (32 KiB, in-place). x buffer: 64x64 (8 KiB).
// Total 40960 B -> 4 blocks/CU.
// ---------------------------------------------------------------------------
__device__ __forceinline__ int cmaj(int row, int col) {
    return ((col >> 3) << 9) + (row << 3) + (col & 7);
}

// ---------------------------------------------------------------------------
// Weight pre-pack (unchanged, proven R5-R15): fp32 (K,N) row-major -> fp16
// fragment order; lane L holds W[kt*16 + 8*(L>>5) + j][nt*32 + (L&31)].
// Fed to the MFMA *A* operand so D = C^T. K zero-padded: L1 39->64 (KT=4),
// L5 295->320 (KT=20), others 256 (KT=16). L9 N 4->32. Tile starts (1KB):
// {0,32,160,288,416,576,704,832,960}, total 976 tiles = 999424 B in d_ws.
// ---------------------------------------------------------------------------
__global__ void pack_w32(const float* __restrict__ w1, const float* __restrict__ w2,
                         const float* __restrict__ w3, const float* __restrict__ w4,
                         const float* __restrict__ w5, const float* __restrict__ w6,
                         const float* __restrict__ w7, const float* __restrict__ w8,
                         const float* __restrict__ w9, _Float16* __restrict__ dst) {
    const int tileStart[10] = {0, 32, 160, 288, 416, 576, 704, 832, 960, 976};
    const int Ks[9] = {39, 256, 256, 256, 295, 256, 256, 256, 256};
    const int Ns[9] = {256, 256, 256, 256, 256, 256, 256, 256, 4};
    const int Tn[9] = {8, 8, 8, 8, 8, 8, 8, 8, 1};
    const float* ws[9] = {w1, w2, w3, w4, w5, w6, w7, w8, w9};

    int g = blockIdx.x * blockDim.x + threadIdx.x;
    int tile = g >> 6, lane = g & 63;
    if (tile >= 976) return;
    int layer = 0;
    while (tile >= tileStart[layer + 1]) layer++;
    int t = tile - tileStart[layer];
    int tn = Tn[layer];
    int kt = t / tn, nt = t - kt * tn;
    int k0 = kt * 16 + (lane >> 5) * 8;
    int n = nt * 32 + (lane & 31);
    const float* w = ws[layer];
    int K = Ks[layer], N = Ns[layer];
    _Float16 v[8];
#pragma unroll
    for (int j = 0; j < 8; j++) {
        int k = k0 + j;
        v[j] = (k < K && n < N) ? (_Float16)w[k * N + n] : (_Float16)0.f;
    }
    *(half8*)(dst + (size_t)tile * 512 + lane * 8) = *(half8*)v;
}

// A-fragment load: base already encodes (lhi, row); offset linear in ks.
// AMODE 0: act. 1: ks>=KS0 from x (layer-5 skip). 2: entirely x (layer 1).
template <int AMODE, int KS0>
__device__ __forceinline__ half8 ldA(const _Float16* aB, const _Float16* xB, int ks) {
    if (AMODE == 2) return *(const half8*)(xB + ks * 1024);
    if (AMODE == 1 && ks >= KS0) return *(const half8*)(xB + (ks - KS0) * 1024);
    return *(const half8*)(aB + ks * 1024);
}

// Two k-steps of MFMA using already-resident W fragments.
template <int AMODE, int KS0>
__device__ __forceinline__ void two_steps(const _Float16* aB0, const _Float16* aB1,
                                          const _Float16* xB0, const _Float16* xB1,
                                          int ks,
                                          half8 wa0, half8 wa1, half8 wb0, half8 wb1,
                                          floatx16& acc00, floatx16& acc10,
                                          floatx16& acc01, floatx16& acc11) {
    half8 a0 = ldA<AMODE, KS0>(aB0, xB0, ks);
    half8 a1 = ldA<AMODE, KS0>(aB1, xB1, ks);
    acc00 = __builtin_amdgcn_mfma_f32_32x32x16_f16(wa0, a0, acc00, 0, 0, 0);
    acc10 = __builtin_amdgcn_mfma_f32_32x32x16_f16(wa1, a0, acc10, 0, 0, 0);
    acc01 = __builtin_amdgcn_mfma_f32_32x32x16_f16(wa0, a1, acc01, 0, 0, 0);
    acc11 = __builtin_amdgcn_mfma_f32_32x32x16_f16(wa1, a1, acc11, 0, 0, 0);
    a0 = ldA<AMODE, KS0>(aB0, xB0, ks + 1);
    a1 = ldA<AMODE, KS0>(aB1, xB1, ks + 1);
    acc00 = __builtin_amdgcn_mfma_f32_32x32x16_f16(wb0, a0, acc00, 0, 0, 0);
    acc10 = __builtin_amdgcn_mfma_f32_32x32x16_f16(wb1, a0, acc10, 0, 0, 0);
    acc01 = __builtin_amdgcn_mfma_f32_32x32x16_f16(wb0, a1, acc01, 0, 0, 0);
    acc11 = __builtin_amdgcn_mfma_f32_32x32x16_f16(wb1, a1, acc11, 0, 0, 0);
}

// ---------------------------------------------------------------------------
// One fused layer: C(64x256) = relu(A(64xK) @ W + b), in-place LDS->LDS.
// R16 = R13's exact proven structure (2m x 2n swapped-operand tile, unroll
// x2 depth-2 W ring, bias folded into acc init, b64 epilogue, (256,4) ->
// 16 waves/CU) with chunk-major A addressing: one LDS base VGPR per
// m-stream, all ksteps via immediate offsets, ~3 VALU per 4-kstep iter.
// ---------------------------------------------------------------------------
template <int KT, int AMODE, int KS0>
__device__ __forceinline__ void layerT(const _Float16* abuf,
                                       const _Float16* __restrict__ xbuf,
                                       const half8* __restrict__ wq,
                                       const float* __restrict__ bias,
                                       _Float16* obuf,
                                       int lane, int wave) {
    static_assert((KT & 3) == 0 && KT >= 4, "KT must be a multiple of 4");
    const int l31 = lane & 31, lhi = lane >> 5;
    // A stream bases: rows l31 (aB0) and 32+l31 (aB1), chunk parity lhi.
    const _Float16* aB0 = abuf + lhi * 512 + l31 * 8;
    const _Float16* aB1 = abuf + lhi * 512 + (32 + l31) * 8;
    const _Float16* xB0 = xbuf + lhi * 512 + l31 * 8;
    const _Float16* xB1 = xbuf + lhi * 512 + (32 + l31) * 8;
    // W frag (kstep ks, n-tile wave*2+n): wl[ks*512 + n*64]
    const half8* wl = wq + (wave * 2) * 64 + lane;
    // Bias -> acc init: acc element g*4+r is channel wave*64 +{0,32}+ lhi*4+g*8+r.
    floatx16 ai0, ai1;
#pragma unroll
    for (int g = 0; g < 4; g++) {
        floatx4 b0 = *(const floatx4*)(bias + wave * 64 + lhi * 4 + g * 8);
        floatx4 b1 = *(const floatx4*)(bias + wave * 64 + 32 + lhi * 4 + g * 8);
#pragma unroll
        for (int r = 0; r < 4; r++) { ai0[g * 4 + r] = b0[r]; ai1[g * 4 + r] = b1[r]; }
    }
    floatx16 acc00 = ai0, acc01 = ai0, acc10 = ai1, acc11 = ai1;
    half8 w0a = wl[0], w0b = wl[64];
    half8 w1a = wl[512], w1b = wl[512 + 64];
#pragma unroll 1
    for (int ks = 0; ks < KT - 4; ks += 4) {
        half8 w2a = wl[(ks + 2) * 512], w2b = wl[(ks + 2) * 512 + 64];
        half8 w3a = wl[(ks + 3) * 512], w3b = wl[(ks + 3) * 512 + 64];
        two_steps<AMODE, KS0>(aB0, aB1, xB0, xB1, ks, w0a, w0b, w1a, w1b,
                              acc00, acc10, acc01, acc11);
        w0a = wl[(ks + 4) * 512]; w0b = wl[(ks + 4) * 512 + 64];
        w1a = wl[(ks + 5) * 512]; w1b = wl[(ks + 5) * 512 + 64];
        two_steps<AMODE, KS0>(aB0, aB1, xB0, xB1, ks + 2, w2a, w2b, w3a, w3b,
                              acc00, acc10, acc01, acc11);
    }
    {   // tail: last 4 k-steps (w0/w1 hold KT-4, KT-3)
        half8 w2a = wl[(KT - 2) * 512], w2b = wl[(KT - 2) * 512 + 64];
        half8 w3a = wl[(KT - 1) * 512], w3b = wl[(KT - 1) * 512 + 64];
        two_steps<AMODE, KS0>(aB0, aB1, xB0, xB1, KT - 4, w0a, w0b, w1a, w1b,
                              acc00, acc10, acc01, acc11);
        two_steps<AMODE, KS0>(aB0, aB1, xB0, xB1, KT - 2, w2a, w2b, w3a, w3b,
                              acc00, acc10, acc01, acc11);
    }
    // In-place safety barrier: all waves' act-reads complete before any write.
    if (AMODE != 2) __syncthreads();
    // Epilogue: relu + fp16 cvt + b64 writes (bias already in acc).
    // col = wave*64 + ni*32 + lhi*4 + g*8 + r -> chunk = wave*8 + ni*4 + g,
    // inner = lhi*4 + r. One base per m-half + immediate offsets.
#pragma unroll
    for (int mi = 0; mi < 2; mi++) {
        _Float16* ob = obuf + wave * 4096 + (mi * 32 + l31) * 8 + lhi * 4;
#pragma unroll
        for (int ni = 0; ni < 2; ni++) {
            const floatx16 accv = (ni == 0) ? (mi == 0 ? acc00 : acc01)
                                            : (mi == 0 ? acc10 : acc11);
#pragma unroll
            for (int g = 0; g < 4; g++) {
                half4v h;
#pragma unroll
                for (int r = 0; r < 4; r++) {
                    float v = accv[g * 4 + r];
                    v = v > 0.f ? v : 0.f;
                    h[r] = (_Float16)v;
                }
                *(half4v*)(ob + (ni * 4 + g) * 512) = h;
            }
        }
    }
}

// Layer 9 (swapped): 256 -> 4 (N padded to 32). Waves 0,1 take m-tiles;
// D[n][m]: lanes 0..31 hold n=r (r<4) for row m=l31 -> one float4 store/lane.
__device__ __forceinline__ void layer9T(const _Float16* abuf,
                                        const half8* __restrict__ wq,
                                        const float* __restrict__ b9,
                                        float* __restrict__ out, long r0,
                                        int lane, int wave) {
    if (wave >= 2) return;
    const int l31 = lane & 31, lhi = lane >> 5;
    const _Float16* aB = abuf + lhi * 512 + (wave * 32 + l31) * 8;
    floatx16 acc = {};
    const half8* wl = wq + lane;
    half8 wc = wl[0];
#pragma unroll 1
    for (int ks = 0; ks < 15; ks++) {
        half8 wn = wl[(ks + 1) * 64];
        half8 a = *(const half8*)(aB + ks * 1024);
        acc = __builtin_amdgcn_mfma_f32_32x32x16_f16(wc, a, acc, 0, 0, 0);
        wc = wn;
    }
    {
        half8 a = *(const half8*)(aB + 15 * 1024);
        acc = __builtin_amdgcn_mfma_f32_32x32x16_f16(wc, a, acc, 0, 0, 0);
    }
    if (lhi == 0) {
        asm volatile("" ::: "memory");
        floatx4 b4 = *(const floatx4*)(b9);
        floatx4 o;
#pragma unroll
        for (int r = 0; r < 4; r++) o[r] = acc[r] + b4[r];
        *(floatx4*)(out + (r0 + wave * 32 + l31) * 4) = o;
    }
}

__global__ __launch_bounds__(256, 4) void mlp_fused(
    const float* __restrict__ x, const _Float16* __restrict__ wpk,
    const float* __restrict__ b1, const float* __restrict__ b2,
    const float* __restrict__ b3, const float* __restrict__ b4,
    const float* __restrict__ b5, const float* __restrict__ b6,
    const float* __restrict__ b7, const float* __restrict__ b8,
    const float* __restrict__ b9, float* __restrict__ out) {
    // Single 32 KiB act buffer + 8 KiB x tile = 40960 B; 4-wave blocks;
    // 4 blocks/CU = 16 waves/CU = 4 waves/SIMD at <=128 total regs/wave.
    __shared__ _Float16 lds[64 * 256 + 64 * 64];
    _Float16* buf = lds;
    _Float16* xbuf = lds + 64 * 256;
    const int tid = threadIdx.x;
    const int lane = tid & 63, wave = tid >> 6;
    const long r0 = (long)blockIdx.x * 64;

    // Stage x (chunk-major): zero pad cols (39..63), fill cols 0..38.
    for (int i = tid; i < 64 * 25; i += 256) {
        int row = i / 25, col = 39 + (i - row * 25);
        xbuf[cmaj(row, col)] = (_Float16)0.f;
    }
    for (int i = tid; i < 64 * 39; i += 256) {
        int row = i / 39, col = i - row * 39;
        xbuf[cmaj(row, col)] = (_Float16)x[r0 * 39 + i];  // contiguous 2496 floats
    }
    __syncthreads();

    const half8* wp = (const half8*)wpk;  // tile = 64 half8 (1 KB)
    const half8* w1q = wp + (size_t)0 * 64;
    const half8* w2q = wp + (size_t)32 * 64;
    const half8* w3q = wp + (size_t)160 * 64;
    const half8* w4q = wp + (size_t)288 * 64;
    const half8* w5q = wp + (size_t)416 * 64;
    const half8* w6q = wp + (size_t)576 * 64;
    const half8* w7q = wp + (size_t)704 * 64;
    const half8* w8q = wp + (size_t)832 * 64;
    const half8* w9q = wp + (size_t)960 * 64;

    layerT<4, 2, 0>(xbuf, xbuf, w1q, b1, buf, lane, wave);   // x -> buf
    __syncthreads();
    layerT<16, 0, 0>(buf, xbuf, w2q, b2, buf, lane, wave);
    __syncthreads();
    layerT<16, 0, 0>(buf, xbuf, w3q, b3, buf, lane, wave);
    __syncthreads();
    layerT<16, 0, 0>(buf, xbuf, w4q, b4, buf, lane, wave);
    __syncthreads();
    layerT<20, 1, 16>(buf, xbuf, w5q, b5, buf, lane, wave);  // [h|x] skip
    __syncthreads();
    layerT<16, 0, 0>(buf, xbuf, w6q, b6, buf, lane, wave);
    __syncthreads();
    layerT<16, 0, 0>(buf, xbuf, w7q, b7, buf, lane, wave);
    __syncthreads();
    layerT<16, 0, 0>(buf, xbuf, w8q, b8, buf, lane, wave);
    __syncthreads();
    layer9T(buf, w9q, b9, out, r0, lane, wave);
}

extern "C" void kernel_launch(void* const* d_in, const int* in_sizes, int n_in,
                              void* d_out, int out_size, void* d_ws, size_t ws_size,
                              hipStream_t stream) {
    const float* x = (const float*)d_in[0];
    const float* w[9];
    const float* b[9];
    for (int i = 0; i < 9; i++) {
        w[i] = (const float*)d_in[1 + 2 * i];
        b[i] = (const float*)d_in[2 + 2 * i];
    }
    _Float16* wpk = (_Float16*)d_ws;  // 999424 B

    pack_w32<<<244, 256, 0, stream>>>(w[0], w[1], w[2], w[3], w[4], w[5], w[6], w[7], w[8], wpk);
    mlp_fused<<<262144 / 64, 256, 0, stream>>>(x, wpk, b[0], b[1], b[2], b[3], b[4],
                                               b[5], b[6], b[7], b[8], (float*)d_out);
}